// Round 1
// baseline (2434.009 us; speedup 1.0000x reference)
//
#include <hip/hip_runtime.h>

// GRU_43387759624777 — Round 1: correctness-first pure-fp32 scan.
// One wave (64 lanes) per batch row. Lane i owns hidden unit i:
//   - w_hh rows i (r-gate), 64+i (z-gate), 128+i (n-gate) live in VGPRs (192 regs)
//   - h[i] in a single register; h[j] broadcast via v_readlane (full-rate VALU)
// Per step: 64 readlanes + 192 FMAs + gate math. T-loop rolled; j-loop unrolled
// so weight-array indices are static (SROA keeps them in VGPRs).

#define HID 64
#define SEQ 1024
#define BATCH 4096

__device__ __forceinline__ float bcast(float v, int srclane) {
  return __int_as_float(__builtin_amdgcn_readlane(__float_as_int(v), srclane));
}

__device__ __forceinline__ float sigm(float v) {
  return 1.0f / (1.0f + __expf(-v));
}

__device__ __forceinline__ float tanh_fast(float v) {
  // tanh(x) = 1 - 2/(exp(2x)+1)
  return 1.0f - 2.0f / (__expf(2.0f * v) + 1.0f);
}

__global__ __launch_bounds__(256) void gru_scan_fp32(
    const float* __restrict__ x,     // [B, T] (INPUT=1 folded)
    const float* __restrict__ w_ih,  // [192, 1]
    const float* __restrict__ w_hh,  // [192, 64]
    const float* __restrict__ b_ih,  // [192]
    const float* __restrict__ b_hh,  // [192]
    const float* __restrict__ w1,    // [32, 64]
    const float* __restrict__ b1,    // [32]
    const float* __restrict__ w2,    // [16, 32]
    const float* __restrict__ b2,    // [16]
    const float* __restrict__ w3,    // [1, 16]
    const float* __restrict__ b3,    // [1]
    float* __restrict__ out)         // [B, 1]
{
  const int w    = threadIdx.x >> 6;   // wave id within block (0..3)
  const int lane = threadIdx.x & 63;
  const int row  = blockIdx.x * 4 + w; // batch row, grid=1024 -> rows 0..4095

  // ---- load recurrent weights into registers (rows lane, 64+lane, 128+lane)
  float wr[HID], wz[HID], wn[HID];
  const float4* whh4 = reinterpret_cast<const float4*>(w_hh);
  #pragma unroll
  for (int j4 = 0; j4 < HID / 4; ++j4) {
    float4 a = whh4[(0   + lane) * (HID / 4) + j4];
    float4 b = whh4[(64  + lane) * (HID / 4) + j4];
    float4 c = whh4[(128 + lane) * (HID / 4) + j4];
    wr[4*j4+0] = a.x; wr[4*j4+1] = a.y; wr[4*j4+2] = a.z; wr[4*j4+3] = a.w;
    wz[4*j4+0] = b.x; wz[4*j4+1] = b.y; wz[4*j4+2] = b.z; wz[4*j4+3] = b.w;
    wn[4*j4+0] = c.x; wn[4*j4+1] = c.y; wn[4*j4+2] = c.z; wn[4*j4+3] = c.w;
  }

  // input-projection constants for this lane's three gates
  const float wir = w_ih[lane];
  const float wiz = w_ih[64 + lane];
  const float win = w_ih[128 + lane];
  // r,z biases combine (b_ih + b_hh); n-gate's b_hh must stay inside r*(...)
  const float br   = b_ih[lane]       + b_hh[lane];
  const float bz   = b_ih[64 + lane]  + b_hh[64 + lane];
  const float bn_i = b_ih[128 + lane];
  const float bn_h = b_hh[128 + lane];

  float h = 0.0f;
  const float* xrow = x + (size_t)row * SEQ;

  for (int tb = 0; tb < SEQ / 64; ++tb) {
    // coalesced: each lane grabs one timestep of this row's input
    float xpack = xrow[tb * 64 + lane];
    for (int s = 0; s < 64; ++s) {
      float xt = bcast(xpack, s);  // uniform dynamic lane index (SGPR) is legal
      float gr = 0.0f, gz = 0.0f, gn = 0.0f;
      #pragma unroll
      for (int j = 0; j < HID; ++j) {
        float hj = bcast(h, j);    // static lane index after unroll
        gr = __fmaf_rn(wr[j], hj, gr);
        gz = __fmaf_rn(wz[j], hj, gz);
        gn = __fmaf_rn(wn[j], hj, gn);
      }
      float r = sigm(gr + __fmaf_rn(xt, wir, br));
      float z = sigm(gz + __fmaf_rn(xt, wiz, bz));
      float n = tanh_fast(__fmaf_rn(xt, win, bn_i) + r * (gn + bn_h));
      h = n + z * (h - n);         // (1-z)*n + z*h
    }
  }

  // ---- MLP head: 64 -> 32 -> 16 -> 1 (leaky relu 0.01 on first two)
  __shared__ float hb[4][HID];
  __shared__ float y1b[4][32];
  __shared__ float y2b[4][16];

  hb[w][lane] = h;
  __syncthreads();

  if (lane < 32) {
    float a = b1[lane];
    #pragma unroll
    for (int j = 0; j < 64; ++j) a = __fmaf_rn(w1[lane * 64 + j], hb[w][j], a);
    y1b[w][lane] = (a > 0.0f) ? a : 0.01f * a;
  }
  __syncthreads();

  if (lane < 16) {
    float a = b2[lane];
    #pragma unroll
    for (int j = 0; j < 32; ++j) a = __fmaf_rn(w2[lane * 32 + j], y1b[w][j], a);
    y2b[w][lane] = (a > 0.0f) ? a : 0.01f * a;
  }
  __syncthreads();

  if (lane == 0) {
    float a = b3[0];
    #pragma unroll
    for (int j = 0; j < 16; ++j) a = __fmaf_rn(w3[j], y2b[w][j], a);
    out[row] = a;
  }
}

extern "C" void kernel_launch(void* const* d_in, const int* in_sizes, int n_in,
                              void* d_out, int out_size, void* d_ws, size_t ws_size,
                              hipStream_t stream) {
  const float* x    = (const float*)d_in[0];
  const float* w_ih = (const float*)d_in[1];
  const float* w_hh = (const float*)d_in[2];
  const float* b_ih = (const float*)d_in[3];
  const float* b_hh = (const float*)d_in[4];
  const float* w1   = (const float*)d_in[5];
  const float* b1   = (const float*)d_in[6];
  const float* w2   = (const float*)d_in[7];
  const float* b2   = (const float*)d_in[8];
  const float* w3   = (const float*)d_in[9];
  const float* b3   = (const float*)d_in[10];
  float* out = (float*)d_out;

  dim3 grid(BATCH / 4);   // 4 waves (rows) per 256-thread block
  dim3 block(256);
  hipLaunchKernelGGL(gru_scan_fp32, grid, block, 0, stream,
                     x, w_ih, w_hh, b_ih, b_hh, w1, b1, w2, b2, w3, b3, out);
}